// Round 2
// baseline (519.286 us; speedup 1.0000x reference)
//
#include <hip/hip_runtime.h>
#include <hip/hip_bf16.h>

#define B_BATCH 512
#define T_SEQ   512
#define F_INP   64
#define H_DIM   128
#define N3H     384
#define HS      136   // h_lds row stride in bf16 elems: 272B = 16*17, 16B-aligned rows, 2-way-only bank aliasing
#define XS      72    // x_lds row stride: 144B = 16*9

typedef float f32x4 __attribute__((ext_vector_type(4)));
typedef __bf16 bf16x8 __attribute__((ext_vector_type(8)));
typedef unsigned short ushort8_t __attribute__((ext_vector_type(8)));

static __device__ __forceinline__ unsigned short f2bf(float f) {
    unsigned int u = __builtin_bit_cast(unsigned int, f);
    u += 0x7FFFu + ((u >> 16) & 1u);   // round-to-nearest-even
    return (unsigned short)(u >> 16);
}

static __device__ __forceinline__ float fast_sigmoid(float x) {
    float t = __builtin_amdgcn_exp2f(-1.442695041f * x);
    return __builtin_amdgcn_rcpf(1.0f + t);
}
static __device__ __forceinline__ float fast_tanh(float x) {
    x = fminf(fmaxf(x, -15.0f), 15.0f);                     // avoid inf/inf NaN
    float t = __builtin_amdgcn_exp2f(-2.885390082f * x);    // e^{-2x}
    return (1.0f - t) * __builtin_amdgcn_rcpf(1.0f + t);
}

static __device__ __forceinline__ bf16x8 ld8(const unsigned short* p) {
    return __builtin_bit_cast(bf16x8, *(const ushort8_t*)p);
}

// 32 blocks x 16 batch rows. 8 waves; wave w owns gate-column tiles {w, w+8, w+16}
// so z/r/hh for hidden cols [16w,16w+16) are wave-local in C-layout.
__global__ __launch_bounds__(512, 1) void gru_kernel(
    const float* __restrict__ inputs, const float* __restrict__ Wx,
    const float* __restrict__ Wh, const float* __restrict__ bias,
    float* __restrict__ hfin)
{
    __shared__ __attribute__((aligned(16))) unsigned short h_lds[2][16 * HS];
    __shared__ __attribute__((aligned(16))) unsigned short x_lds[2][16 * XS];

    const int tid  = threadIdx.x;
    const int w    = tid >> 6;
    const int lane = tid & 63;
    const int m    = lane & 15;     // row (A/M index) or col (B/N, C/D col index)
    const int q    = lane >> 4;     // quad
    const int b0   = blockIdx.x * 16;

    // ---- load weight B-fragments into registers (persist across all 512 steps) ----
    bf16x8 whB[3][4];   // [gate][k-step]  rec: K=128 -> 4 k-steps
    bf16x8 wxB[3][2];   // [gate][k-step]  xw:  K=64  -> 2 k-steps
    float brec[3], bin[3];
#pragma unroll
    for (int g = 0; g < 3; ++g) {
        const int col = 16 * (w + 8 * g) + m;
#pragma unroll
        for (int k = 0; k < 4; ++k) {
            ushort8_t tmp;
#pragma unroll
            for (int j = 0; j < 8; ++j) {
                const int row = 32 * k + 8 * q + j;
                tmp[j] = f2bf(Wh[row * N3H + col]);
            }
            whB[g][k] = __builtin_bit_cast(bf16x8, tmp);
        }
#pragma unroll
        for (int k = 0; k < 2; ++k) {
            ushort8_t tmp;
#pragma unroll
            for (int j = 0; j < 8; ++j) {
                const int row = 32 * k + 8 * q + j;
                tmp[j] = f2bf(Wx[row * N3H + col]);
            }
            wxB[g][k] = __builtin_bit_cast(bf16x8, tmp);
        }
        bin[g]  = bias[col];          // b[0] row
        brec[g] = bias[N3H + col];    // b[1] row
    }

    // zero h buffer 0 (h(0) = 0)
    for (int i = tid; i < 16 * HS; i += 512) h_lds[0][i] = 0;

    // stage x(t) (fp32 global -> bf16 LDS), 16 rows x 64 features
    auto stage = [&](int t, int buf) {
        const int sm = tid >> 5;
        const int f  = (tid & 31) * 2;
        const float* src = inputs + ((size_t)(b0 + sm) * T_SEQ + t) * 65 + f;
        unsigned int packed = (unsigned int)f2bf(src[0]) | ((unsigned int)f2bf(src[1]) << 16);
        *(unsigned int*)&x_lds[buf][sm * XS + f] = packed;
    };

    stage(0, 0);
    __syncthreads();

    // xw(0) = x(0) @ Wx + b_in
    f32x4 xw_cur[3];
    {
        bf16x8 xa[2];
#pragma unroll
        for (int k = 0; k < 2; ++k) xa[k] = ld8(&x_lds[0][m * XS + 32 * k + 8 * q]);
#pragma unroll
        for (int g = 0; g < 3; ++g) {
            f32x4 acc = { bin[g], bin[g], bin[g], bin[g] };
#pragma unroll
            for (int k = 0; k < 2; ++k)
                acc = __builtin_amdgcn_mfma_f32_16x16x32_bf16(xa[k], wxB[g][k], acc, 0, 0, 0);
            xw_cur[g] = acc;
        }
    }
    stage(1, 1);

    f32x4 hreg = { 0.f, 0.f, 0.f, 0.f };   // h for rows 4q+i, col 16w+m (C-layout)

    for (int t = 0; t < T_SEQ; ++t) {
        __syncthreads();   // guards: h_lds[t&1] writes (prev iter), x_lds staging (prev iter)
        const int pc = t & 1, pn = (t + 1) & 1;

        // rec(t) = h(t) @ Wh + b_rec
        bf16x8 ha[4];
#pragma unroll
        for (int k = 0; k < 4; ++k) ha[k] = ld8(&h_lds[pc][m * HS + 32 * k + 8 * q]);
        f32x4 racc[3];
#pragma unroll
        for (int g = 0; g < 3; ++g) {
            f32x4 acc = { brec[g], brec[g], brec[g], brec[g] };
#pragma unroll
            for (int k = 0; k < 4; ++k)
                acc = __builtin_amdgcn_mfma_f32_16x16x32_bf16(ha[k], whB[g][k], acc, 0, 0, 0);
            racc[g] = acc;
        }

        // xw(t+1) (independent of h -> overlaps the rec chain)
        f32x4 xw_next[3];
        if (t < T_SEQ - 1) {
            bf16x8 xa[2];
#pragma unroll
            for (int k = 0; k < 2; ++k) xa[k] = ld8(&x_lds[pn][m * XS + 32 * k + 8 * q]);
#pragma unroll
            for (int g = 0; g < 3; ++g) {
                f32x4 acc = { bin[g], bin[g], bin[g], bin[g] };
#pragma unroll
                for (int k = 0; k < 2; ++k)
                    acc = __builtin_amdgcn_mfma_f32_16x16x32_bf16(xa[k], wxB[g][k], acc, 0, 0, 0);
                xw_next[g] = acc;
            }
        }
        if (t < T_SEQ - 2) stage(t + 2, pc);

        // gates (wave-local: z/r/hh are tiles g=0/1/2, same cols)
        f32x4 hnew;
#pragma unroll
        for (int i = 0; i < 4; ++i) {
            const float z  = fast_sigmoid(xw_cur[0][i] + racc[0][i]);
            const float r  = fast_sigmoid(xw_cur[1][i] + racc[1][i]);
            const float hh = fast_tanh(xw_cur[2][i] + r * racc[2][i]);
            hnew[i] = hh + z * (hreg[i] - hh);
        }
        hreg = hnew;

        // write h(t+1) as bf16 into the other buffer (A-matrix layout [row][hcol])
        {
            const int col = 16 * w + m;
#pragma unroll
            for (int i = 0; i < 4; ++i) {
                const int row = 4 * q + i;
                h_lds[pn][row * HS + col] = f2bf(hnew[i]);
            }
        }
        if (t < T_SEQ - 1) {
#pragma unroll
            for (int g = 0; g < 3; ++g) xw_cur[g] = xw_next[g];
        }
    }

    // write final hidden state (fp32) to workspace
    {
        const int col = 16 * w + m;
#pragma unroll
        for (int i = 0; i < 4; ++i) {
            const int row = b0 + 4 * q + i;
            hfin[row * H_DIM + col] = hreg[i];
        }
    }
}

// One block (1 wave) per batch row: hidden + W_state[idx] -> w1/ReLU/BN -> w2
__global__ __launch_bounds__(64) void mlp_kernel(
    const float* __restrict__ inputs, const float* __restrict__ hfin,
    const float* __restrict__ W_state, const float* __restrict__ w1,
    const float* __restrict__ b1, const float* __restrict__ gamma,
    const float* __restrict__ beta, const float* __restrict__ mean,
    const float* __restrict__ var, const float* __restrict__ w2,
    const float* __restrict__ b2, float* __restrict__ out)
{
    __shared__ float sh[H_DIM];
    const int r = blockIdx.x;
    const int j = threadIdx.x;

    const float sf = inputs[((size_t)r * T_SEQ + (T_SEQ - 1)) * 65 + 64];
    int si = (int)sf;
    si = si < 0 ? 0 : (si > 2 ? 2 : si);

    for (int k = j; k < H_DIM; k += 64)
        sh[k] = hfin[r * H_DIM + k] + W_state[si * H_DIM + k];
    __syncthreads();

    float acc = b1[j];
#pragma unroll 8
    for (int k = 0; k < H_DIM; ++k)
        acc = fmaf(sh[k], w1[k * 64 + j], acc);
    acc = fmaxf(acc, 0.0f);
    acc = (acc - mean[j]) * rsqrtf(var[j] + 1e-3f) * gamma[j] + beta[j];

    float v = acc * w2[j];
#pragma unroll
    for (int off = 32; off > 0; off >>= 1) v += __shfl_down(v, off);
    if (j == 0) out[r] = v + b2[0];
}

extern "C" void kernel_launch(void* const* d_in, const int* in_sizes, int n_in,
                              void* d_out, int out_size, void* d_ws, size_t ws_size,
                              hipStream_t stream) {
    (void)in_sizes; (void)n_in; (void)out_size; (void)ws_size;
    const float* inputs  = (const float*)d_in[0];
    const float* Wx      = (const float*)d_in[1];
    const float* Wh      = (const float*)d_in[2];
    const float* bias    = (const float*)d_in[3];
    const float* W_state = (const float*)d_in[4];
    const float* w1      = (const float*)d_in[5];
    const float* b1      = (const float*)d_in[6];
    const float* gamma   = (const float*)d_in[7];
    const float* beta    = (const float*)d_in[8];
    const float* mean    = (const float*)d_in[9];
    const float* var     = (const float*)d_in[10];
    const float* w2      = (const float*)d_in[11];
    const float* b2      = (const float*)d_in[12];
    float* hfin = (float*)d_ws;   // 512*128 fp32 = 256 KB scratch
    float* out  = (float*)d_out;

    gru_kernel<<<32, 512, 0, stream>>>(inputs, Wx, Wh, bias, hfin);
    mlp_kernel<<<512, 64, 0, stream>>>(inputs, hfin, W_state, w1, b1, gamma,
                                       beta, mean, var, w2, b2, out);
}

// Round 3
// 517.130 us; speedup vs baseline: 1.0042x; 1.0042x over previous
//
#include <hip/hip_runtime.h>
#include <hip/hip_bf16.h>

#define T_SEQ   512
#define H_DIM   128
#define N3H     384

typedef float f32x4 __attribute__((ext_vector_type(4)));
typedef float f32x4u __attribute__((ext_vector_type(4), aligned(4)));
typedef __bf16 bf16x8 __attribute__((ext_vector_type(8)));
typedef unsigned short us8 __attribute__((ext_vector_type(8)));
typedef unsigned short us4 __attribute__((ext_vector_type(4)));

static __device__ __forceinline__ unsigned short f2bf(float f) {
    unsigned int u = __builtin_bit_cast(unsigned int, f);
    u += 0x7FFFu + ((u >> 16) & 1u);   // round-to-nearest-even
    return (unsigned short)(u >> 16);
}

static __device__ __forceinline__ float fast_sigmoid(float x) {
    float t = __builtin_amdgcn_exp2f(-1.442695041f * x);
    return __builtin_amdgcn_rcpf(1.0f + t);
}
static __device__ __forceinline__ float fast_tanh(float x) {
    x = fminf(fmaxf(x, -15.0f), 15.0f);
    float t = __builtin_amdgcn_exp2f(-2.885390082f * x);    // e^{-2x}
    return (1.0f - t) * __builtin_amdgcn_rcpf(1.0f + t);
}

// Barrier that orders LDS only — does NOT drain vmcnt, so register prefetch
// loads stay in flight across it. 0xC07F = lgkmcnt(0), vmcnt/expcnt = max.
static __device__ __forceinline__ void lds_barrier() {
    asm volatile("" ::: "memory");
    __builtin_amdgcn_s_waitcnt(0xC07F);
    __builtin_amdgcn_s_barrier();
    asm volatile("" ::: "memory");
}

static __device__ __forceinline__ bf16x8 ld8(const unsigned short* p) {
    return __builtin_bit_cast(bf16x8, *(const us8*)p);
}

// 32 blocks x 16 batch rows, 8 waves (512 thr). Wave w owns gate N-tiles
// {w, w+8, w+16} => z/r/hh for hidden cols [16w,16w+16) are wave-local.
// h LDS: 16 rows x 128 cols bf16, row stride 256B, 16B-chunk XOR-swizzle
// (phys_chunk = logical_chunk ^ (row&7)) -> conflict-free-ish b128 reads.
__global__ __launch_bounds__(512, 1) void gru_kernel(
    const float* __restrict__ inputs, const float* __restrict__ Wx,
    const float* __restrict__ Wh, const float* __restrict__ bias,
    float* __restrict__ hfin)
{
    __shared__ __attribute__((aligned(16))) unsigned short hb[2][16 * 128];
    __shared__ __attribute__((aligned(16))) unsigned short xb[2][16 * 64];

    const int tid  = threadIdx.x;
    const int w    = tid >> 6;
    const int lane = tid & 63;
    const int m    = lane & 15;
    const int q    = lane >> 4;
    const int b0   = blockIdx.x * 16;

    // ---- weight B-fragments in registers for all 512 steps ----
    bf16x8 whB[3][4];
    bf16x8 wxB[3][2];
    float brec[3], bin[3];
#pragma unroll
    for (int g = 0; g < 3; ++g) {
        const int col = 16 * (w + 8 * g) + m;
#pragma unroll
        for (int k = 0; k < 4; ++k) {
            us8 tmp;
#pragma unroll
            for (int j = 0; j < 8; ++j) tmp[j] = f2bf(Wh[(32 * k + 8 * q + j) * N3H + col]);
            whB[g][k] = __builtin_bit_cast(bf16x8, tmp);
        }
#pragma unroll
        for (int k = 0; k < 2; ++k) {
            us8 tmp;
#pragma unroll
            for (int j = 0; j < 8; ++j) tmp[j] = f2bf(Wx[(32 * k + 8 * q + j) * N3H + col]);
            wxB[g][k] = __builtin_bit_cast(bf16x8, tmp);
        }
        bin[g]  = bias[col];
        brec[g] = bias[N3H + col];
    }

    // ---- loop-invariant LDS offsets (ushort elements) ----
    int hro[4], hwo[4], xro[2];
#pragma unroll
    for (int k = 0; k < 4; ++k) hro[k] = m * 128 + (((4 * k + q) ^ (m & 7)) * 8);
#pragma unroll
    for (int i = 0; i < 4; ++i) {
        const int row = 4 * q + i;
        hwo[i] = row * 128 + (((2 * w + (m >> 3)) ^ (row & 7)) * 8) + (m & 7);
    }
#pragma unroll
    for (int k = 0; k < 2; ++k) xro[k] = m * 64 + (((4 * k + q) ^ (m & 7)) * 8);

    // staging map: threads 0..255, one float4 (row sr, cols 4*sc..4*sc+3)
    const int sr = tid >> 4, sc = tid & 15;
    const int xwoff = sr * 64 + (((sc >> 1) ^ (sr & 7)) * 8) + (sc & 1) * 4;
    const float* xsrc = inputs + ((size_t)(b0 + sr) * T_SEQ) * 65 + sc * 4;

    auto xpack = [&](f32x4u v) -> us4 {
        us4 r; r[0] = f2bf(v[0]); r[1] = f2bf(v[1]); r[2] = f2bf(v[2]); r[3] = f2bf(v[3]);
        return r;
    };

    // zero h(0) buffer
    {
        unsigned int* p = (unsigned int*)hb[0];
        for (int i = tid; i < 1024; i += 512) p[i] = 0;
    }
    // direct-stage x(0), x(1)
    if (tid < 256) {
        f32x4u v0 = *(const f32x4u*)(xsrc + 0 * 65);
        f32x4u v1 = *(const f32x4u*)(xsrc + 1 * 65);
        *(us4*)&xb[0][xwoff] = xpack(v0);
        *(us4*)&xb[1][xwoff] = xpack(v1);
    }
    lds_barrier();

    // xw(0) from xb[0]
    f32x4 xw_cur[3];
    {
        bf16x8 xa[2];
#pragma unroll
        for (int k = 0; k < 2; ++k) xa[k] = ld8(&xb[0][xro[k]]);
#pragma unroll
        for (int g = 0; g < 3; ++g) {
            f32x4 acc = { bin[g], bin[g], bin[g], bin[g] };
            acc = __builtin_amdgcn_mfma_f32_16x16x32_bf16(xa[0], wxB[g][0], acc, 0, 0, 0);
            acc = __builtin_amdgcn_mfma_f32_16x16x32_bf16(xa[1], wxB[g][1], acc, 0, 0, 0);
            xw_cur[g] = acc;
        }
    }

    f32x4u pf0 = {}, pf1 = {};
    if (tid < 256) pf0 = *(const f32x4u*)(xsrc + 2 * 65);   // x(2)

    f32x4 hreg = { 0.f, 0.f, 0.f, 0.f };

    // one GRU step; parities passed as compile-time-constant pointers/refs
    auto step = [&](int t, f32x4u& pfLoad, f32x4u& pfUse,
                    const unsigned short* hcur, unsigned short* hnxt,
                    const unsigned short* xnxt, unsigned short* xwr) {
        // issue prefetch for x(t+3) FIRST (before barrier; spans it)
        if (tid < 256 && t <= T_SEQ - 4) pfLoad = *(const f32x4u*)(xsrc + (t + 3) * 65);

        lds_barrier();

        // rec(t) = h(t) @ Wh + b_rec   (two 2-MFMA chains per gate)
        bf16x8 ha[4];
#pragma unroll
        for (int k = 0; k < 4; ++k) ha[k] = ld8(&hcur[hro[k]]);
        f32x4 racc[3];
#pragma unroll
        for (int g = 0; g < 3; ++g) {
            f32x4 a1 = { brec[g], brec[g], brec[g], brec[g] };
            a1 = __builtin_amdgcn_mfma_f32_16x16x32_bf16(ha[0], whB[g][0], a1, 0, 0, 0);
            a1 = __builtin_amdgcn_mfma_f32_16x16x32_bf16(ha[1], whB[g][1], a1, 0, 0, 0);
            f32x4 a2 = { 0.f, 0.f, 0.f, 0.f };
            a2 = __builtin_amdgcn_mfma_f32_16x16x32_bf16(ha[2], whB[g][2], a2, 0, 0, 0);
            a2 = __builtin_amdgcn_mfma_f32_16x16x32_bf16(ha[3], whB[g][3], a2, 0, 0, 0);
            racc[g] = a1 + a2;
        }

        // xw(t+1) from xnxt (independent of h)
        f32x4 xw_next[3];
        if (t < T_SEQ - 1) {
            bf16x8 xa[2];
#pragma unroll
            for (int k = 0; k < 2; ++k) xa[k] = ld8(&xnxt[xro[k]]);
#pragma unroll
            for (int g = 0; g < 3; ++g) {
                f32x4 acc = { bin[g], bin[g], bin[g], bin[g] };
                acc = __builtin_amdgcn_mfma_f32_16x16x32_bf16(xa[0], wxB[g][0], acc, 0, 0, 0);
                acc = __builtin_amdgcn_mfma_f32_16x16x32_bf16(xa[1], wxB[g][1], acc, 0, 0, 0);
                xw_next[g] = acc;
            }
        }

        // consume prefetched x(t+2): convert + LDS write (drains during gates)
        if (tid < 256 && t <= T_SEQ - 3) *(us4*)&xwr[xwoff] = xpack(pfUse);

        // gates
        f32x4 hnew;
#pragma unroll
        for (int i = 0; i < 4; ++i) {
            const float z  = fast_sigmoid(xw_cur[0][i] + racc[0][i]);
            const float r  = fast_sigmoid(xw_cur[1][i] + racc[1][i]);
            const float hh = fast_tanh(xw_cur[2][i] + r * racc[2][i]);
            hnew[i] = hh + z * (hreg[i] - hh);
        }
        hreg = hnew;

        // write h(t+1) bf16 (swizzled b16 scatter)
#pragma unroll
        for (int i = 0; i < 4; ++i) hnxt[hwo[i]] = f2bf(hnew[i]);

        if (t < T_SEQ - 1) {
#pragma unroll
            for (int g = 0; g < 3; ++g) xw_cur[g] = xw_next[g];
        }
    };

    for (int t = 0; t < T_SEQ; t += 2) {
        step(t,     pf1, pf0, hb[0], hb[1], xb[1], xb[0]);
        step(t + 1, pf0, pf1, hb[1], hb[0], xb[0], xb[1]);
    }

    // final hidden state (fp32)
    {
        const int col = 16 * w + m;
#pragma unroll
        for (int i = 0; i < 4; ++i)
            hfin[(b0 + 4 * q + i) * H_DIM + col] = hreg[i];
    }
}

// One wave per batch row: hidden + W_state[idx] -> w1/ReLU/BN -> w2
__global__ __launch_bounds__(64) void mlp_kernel(
    const float* __restrict__ inputs, const float* __restrict__ hfin,
    const float* __restrict__ W_state, const float* __restrict__ w1,
    const float* __restrict__ b1, const float* __restrict__ gamma,
    const float* __restrict__ beta, const float* __restrict__ mean,
    const float* __restrict__ var, const float* __restrict__ w2,
    const float* __restrict__ b2, float* __restrict__ out)
{
    __shared__ float sh[H_DIM];
    const int r = blockIdx.x;
    const int j = threadIdx.x;

    const float sf = inputs[((size_t)r * T_SEQ + (T_SEQ - 1)) * 65 + 64];
    int si = (int)sf;
    si = si < 0 ? 0 : (si > 2 ? 2 : si);

    for (int k = j; k < H_DIM; k += 64)
        sh[k] = hfin[r * H_DIM + k] + W_state[si * H_DIM + k];
    __syncthreads();

    float acc = b1[j];
#pragma unroll 8
    for (int k = 0; k < H_DIM; ++k)
        acc = fmaf(sh[k], w1[k * 64 + j], acc);
    acc = fmaxf(acc, 0.0f);
    acc = (acc - mean[j]) * rsqrtf(var[j] + 1e-3f) * gamma[j] + beta[j];

    float v = acc * w2[j];
#pragma unroll
    for (int off = 32; off > 0; off >>= 1) v += __shfl_down(v, off);
    if (j == 0) out[r] = v + b2[0];
}

extern "C" void kernel_launch(void* const* d_in, const int* in_sizes, int n_in,
                              void* d_out, int out_size, void* d_ws, size_t ws_size,
                              hipStream_t stream) {
    (void)in_sizes; (void)n_in; (void)out_size; (void)ws_size;
    const float* inputs  = (const float*)d_in[0];
    const float* Wx      = (const float*)d_in[1];
    const float* Wh      = (const float*)d_in[2];
    const float* bias    = (const float*)d_in[3];
    const float* W_state = (const float*)d_in[4];
    const float* w1      = (const float*)d_in[5];
    const float* b1      = (const float*)d_in[6];
    const float* gamma   = (const float*)d_in[7];
    const float* beta    = (const float*)d_in[8];
    const float* mean    = (const float*)d_in[9];
    const float* var     = (const float*)d_in[10];
    const float* w2      = (const float*)d_in[11];
    const float* b2      = (const float*)d_in[12];
    float* hfin = (float*)d_ws;   // 512*128 fp32 = 256 KB scratch
    float* out  = (float*)d_out;

    gru_kernel<<<32, 512, 0, stream>>>(inputs, Wx, Wh, bias, hfin);
    mlp_kernel<<<512, 64, 0, stream>>>(inputs, hfin, W_state, w1, b1, gamma,
                                       beta, mean, var, w2, b2, out);
}